// Round 3
// baseline (10326.543 us; speedup 1.0000x reference)
//
#include <hip/hip_runtime.h>

typedef unsigned short u16;
typedef unsigned int   u32;

typedef __bf16 bf16x8 __attribute__((ext_vector_type(8)));
typedef u16    u16x8  __attribute__((ext_vector_type(8)));
typedef float  f32x4  __attribute__((ext_vector_type(4)));

#define B_    32
#define S_    512
#define I_    512
#define H_    1024
#define NBLK  128   // blocks; each owns H_/NBLK = 8 hidden units
#define HU    8
#define MAGIC 0x13579BDFu

__device__ __forceinline__ u16 f2bf(float f) {
    union { float f; u32 i; } c; c.f = f;
    u32 lsb = (c.i >> 16) & 1u;
    c.i += 0x7fffu + lsb;                 // round-to-nearest-even
    return (u16)(c.i >> 16);
}
__device__ __forceinline__ float sigmoid_(float x) {
    return 1.0f / (1.0f + __expf(-x));
}
__device__ __forceinline__ float tanh_(float x) {
    return 2.0f / (1.0f + __expf(-2.0f * x)) - 1.0f;
}

// Software grid barrier (plain launch, 128 blocks co-resident at
// 1 block/CU on 256 CUs). Monotonic counter, agent-scope fences give
// cross-XCD visibility of the plain bf16 h stores (L2 wb/inv).
__device__ __forceinline__ void grid_bar(u32* cnt, u32 target) {
    __syncthreads();
    if (threadIdx.x == 0) {
        __threadfence();   // release: publish this block's h stores
        __hip_atomic_fetch_add(cnt, 1u, __ATOMIC_RELAXED, __HIP_MEMORY_SCOPE_AGENT);
        while (__hip_atomic_load(cnt, __ATOMIC_RELAXED, __HIP_MEMORY_SCOPE_AGENT) < target)
            __builtin_amdgcn_s_sleep(1);
        __threadfence();   // acquire: invalidate caches before reading others' h
    }
    __syncthreads();
}

// Persistent LSTM (fp32 I/O, bf16 MFMA compute):
// Block owns 8 hidden units (= 32 gate columns). [U;W] slice converted
// fp32->bf16 once into registers (48 bf16x8 B-fragments = 192 VGPRs).
// 4 waves: (row-tile rt, col-tile ct) of the 32x32 gate tile, K=1536 fused,
// mfma_f32_16x16x32_bf16. x@W MFMAs run BEFORE the barrier (h-independent).
// h feeds back as bf16 via d_ws; out gets full fp32 h/c.
__global__ void __launch_bounds__(256, 1)
lstm_kernel(const float* __restrict__ X,
            const float* __restrict__ w_i, const float* __restrict__ u_i, const float* __restrict__ b_i,
            const float* __restrict__ w_f, const float* __restrict__ u_f, const float* __restrict__ b_f,
            const float* __restrict__ w_c, const float* __restrict__ u_c, const float* __restrict__ b_c,
            const float* __restrict__ w_o, const float* __restrict__ u_o, const float* __restrict__ b_o,
            float* __restrict__ out, u16* __restrict__ hbuf,
            u32* __restrict__ barflag, u32* __restrict__ barcnt)
{
    __shared__ float gbuf[32 * 33];   // raw gates, +1 col pad

    const int tid  = threadIdx.x;
    const int wave = tid >> 6;
    const int lane = tid & 63;
    const int rt   = wave >> 1;       // row tile (batch 16*rt..)
    const int ct   = wave & 1;        // col tile (gate cols 16*ct..)
    const int quad = lane >> 4;
    const int l16  = lane & 15;
    const int hu0  = blockIdx.x * HU;

    // ---- B-operand fragments into registers (once), fp32 -> bf16 ----
    // block-local gate col: 0..31 = gate g (i,f,c,o) * 8 + unit u
    const int col = ct * 16 + l16;
    const int g   = col >> 3;
    const int u   = col & 7;
    const float* Ucol = ((g == 0) ? u_i : (g == 1) ? u_f : (g == 2) ? u_c : u_o) + hu0 + u;
    const float* Wcol = ((g == 0) ? w_i : (g == 1) ? w_f : (g == 2) ? w_c : w_o) + hu0 + u;

    u16x8 bfr[48];                    // B[k = kb*32 + quad*8 + j][col]
    #pragma unroll
    for (int kb = 0; kb < 32; ++kb) { // K 0..1023: U rows
        #pragma unroll
        for (int j = 0; j < 8; ++j) {
            int k = kb * 32 + quad * 8 + j;
            bfr[kb][j] = f2bf(Ucol[k * H_]);
        }
    }
    #pragma unroll
    for (int kb = 32; kb < 48; ++kb) { // K 1024..1535: W rows
        #pragma unroll
        for (int j = 0; j < 8; ++j) {
            int k = kb * 32 + quad * 8 + j - 1024;
            bfr[kb][j] = f2bf(Wcol[k * H_]);
        }
    }

    // ---- update-phase ownership: thread -> (batch ub, unit uu) ----
    const int ub   = tid >> 3;        // batch 0..31
    const int uu   = tid & 7;         // unit  0..7
    const int unit = hu0 + uu;
    hbuf[ub * H_ + unit] = 0;         // h0 = 0 in buffer 0

    const float bia = b_i[unit];
    const float bif = b_f[unit];
    const float bic = b_c[unit];
    const float bio = b_o[unit];
    float cstate = 0.0f;

    const int    arow = rt * 16 + l16;                      // batch row this lane feeds to A
    const float* xrow = X + arow * (S_ * I_) + quad * 8;    // A[m][k]: m=lane&15(+16rt), k=quad*8+j

    // ---- barrier init handshake (d_ws is poison-filled each launch) ----
    if (blockIdx.x == 0 && tid == 0) {
        __hip_atomic_store(barcnt, 0u, __ATOMIC_RELAXED, __HIP_MEMORY_SCOPE_AGENT);
        __hip_atomic_store(barflag, MAGIC, __ATOMIC_RELEASE, __HIP_MEMORY_SCOPE_AGENT);
    }
    if (tid == 0) {
        while (__hip_atomic_load(barflag, __ATOMIC_ACQUIRE, __HIP_MEMORY_SCOPE_AGENT) != MAGIC)
            __builtin_amdgcn_s_sleep(1);
    }

    u32 round = 1;
    for (int t = 0; t < S_; ++t) {
        // ---- x_t @ W: h-independent, runs before the barrier ----
        f32x4 acc = {0.f, 0.f, 0.f, 0.f};
        const float* xk = xrow + t * I_;
        #pragma unroll
        for (int kb = 0; kb < 16; ++kb) {
            f32x4 lo = *(const f32x4*)(xk + kb * 32);
            f32x4 hi = *(const f32x4*)(xk + kb * 32 + 4);
            u16x8 af;
            af[0] = f2bf(lo[0]); af[1] = f2bf(lo[1]); af[2] = f2bf(lo[2]); af[3] = f2bf(lo[3]);
            af[4] = f2bf(hi[0]); af[5] = f2bf(hi[1]); af[6] = f2bf(hi[2]); af[7] = f2bf(hi[3]);
            acc = __builtin_amdgcn_mfma_f32_16x16x32_bf16(
                      __builtin_bit_cast(bf16x8, af),
                      __builtin_bit_cast(bf16x8, bfr[32 + kb]), acc, 0, 0, 0);
        }

        grid_bar(barcnt, round * NBLK);   // h(t-1) now visible from all blocks
        ++round;

        // ---- h(t-1) @ U (h stored as bf16) ----
        const u16* hprev = hbuf + (t & 1) * (B_ * H_) + arow * H_ + quad * 8;
        #pragma unroll
        for (int kb = 0; kb < 32; ++kb) {
            bf16x8 a = *(const bf16x8*)(hprev + kb * 32);
            acc = __builtin_amdgcn_mfma_f32_16x16x32_bf16(
                      a, __builtin_bit_cast(bf16x8, bfr[kb]), acc, 0, 0, 0);
        }

        // C/D layout: D[row = quad*4 + r][col = lane&15] (+16 per tile)
        {
            const int r0 = rt * 16 + quad * 4;
            #pragma unroll
            for (int r = 0; r < 4; ++r)
                gbuf[(r0 + r) * 33 + col] = acc[r];
        }
        __syncthreads();

        // gates -> c,h update (c stays in an fp32 register all 512 steps)
        {
            float gi = gbuf[ub * 33 + uu]      + bia;
            float gf = gbuf[ub * 33 + 8 + uu]  + bif;
            float gc = gbuf[ub * 33 + 16 + uu] + bic;
            float go = gbuf[ub * 33 + 24 + uu] + bio;
            float it  = sigmoid_(gi);
            float ft  = sigmoid_(gf);
            float ctl = tanh_(gc);
            float ot  = sigmoid_(go);
            cstate = ft * cstate + it * ctl;
            float h = ot * tanh_(cstate);
            hbuf[((t + 1) & 1) * (B_ * H_) + ub * H_ + unit] = f2bf(h);  // bf16 feedback
            out[ub * (S_ * H_) + t * H_ + unit] = h;                     // fp32 hidden_seq
            if (t == S_ - 1) {
                out[B_ * S_ * H_ + ub * H_ + unit] = h;                  // h_t
                out[B_ * S_ * H_ + B_ * H_ + ub * H_ + unit] = cstate;   // c_t
            }
        }
        // next iteration's grid_bar separates this h(t) write from reads
    }
}

extern "C" void kernel_launch(void* const* d_in, const int* in_sizes, int n_in,
                              void* d_out, int out_size, void* d_ws, size_t ws_size,
                              hipStream_t stream) {
    const float* X   = (const float*)d_in[0];
    const float* w_i = (const float*)d_in[1];
    const float* u_i = (const float*)d_in[2];
    const float* b_i = (const float*)d_in[3];
    const float* w_f = (const float*)d_in[4];
    const float* u_f = (const float*)d_in[5];
    const float* b_f = (const float*)d_in[6];
    const float* w_c = (const float*)d_in[7];
    const float* u_c = (const float*)d_in[8];
    const float* b_c = (const float*)d_in[9];
    const float* w_o = (const float*)d_in[10];
    const float* u_o = (const float*)d_in[11];
    const float* b_o = (const float*)d_in[12];
    float* out = (float*)d_out;

    // d_ws layout: [0,131072) h double buffer (2*32*1024 bf16)
    //              [131072, +4)   barrier init flag
    //              [131200, +4)   barrier counter (separate cacheline)
    u16* hbuf    = (u16*)d_ws;
    u32* barflag = (u32*)((char*)d_ws + 131072);
    u32* barcnt  = (u32*)((char*)d_ws + 131200);

    hipLaunchKernelGGL(lstm_kernel, dim3(NBLK), dim3(256), 0, stream,
                       X, w_i, u_i, b_i, w_f, u_f, b_f, w_c, u_c, b_c,
                       w_o, u_o, b_o, out, hbuf, barflag, barcnt);
}

// Round 4
// 7080.798 us; speedup vs baseline: 1.4584x; 1.4584x over previous
//
#include <hip/hip_runtime.h>

typedef unsigned short u16;
typedef unsigned int   u32;

typedef __bf16 bf16x8 __attribute__((ext_vector_type(8)));
typedef float  f32x4  __attribute__((ext_vector_type(4)));

#define B_    32
#define S_    512
#define I_    512
#define H_    1024
#define NBLK  128                 // blocks; each owns H_/NBLK = 8 hidden units
#define HU    8
#define SLOT_ELEMS (B_ * H_)      // one h snapshot: 32768 u16 = 64 KB

__device__ __forceinline__ u16 bf16bits(float f) {
    __bf16 b = (__bf16)f;                       // HW RNE convert on gfx950
    return __builtin_bit_cast(u16, b);
}
__device__ __forceinline__ float sigmoid_(float x) {
    return 1.0f / (1.0f + __expf(-x));
}
__device__ __forceinline__ float tanh_(float x) {
    return 2.0f / (1.0f + __expf(-2.0f * x)) - 1.0f;
}

// Persistent LSTM (fp32 I/O, bf16 MFMA compute), fence-free step protocol:
//  - h exchanged via agent-scope (sc1, IC-coherent) atomic stores; readers use
//    plain dwordx4 loads from a per-step ring slot (first touch is always
//    after the producing barrier -> no stale L2 line can exist), or sc1
//    atomic loads in the small-workspace fallback.
//  - barrier: per-block slot array; block b stores round into slot[b], lanes
//    0..127 poll one slot each (signed compare beats the 0xAA ws poison; no
//    init handshake, no serialized atomics, no __threadfence / buffer_inv).
//  - x_t @ W MFMAs run between arrival and poll (hidden in barrier skew).
__global__ void __launch_bounds__(256, 1)
lstm_kernel(const float* __restrict__ X,
            const float* __restrict__ w_i, const float* __restrict__ u_i, const float* __restrict__ b_i,
            const float* __restrict__ w_f, const float* __restrict__ u_f, const float* __restrict__ b_f,
            const float* __restrict__ w_c, const float* __restrict__ u_c, const float* __restrict__ b_c,
            const float* __restrict__ w_o, const float* __restrict__ u_o, const float* __restrict__ b_o,
            float* __restrict__ out, u16* __restrict__ hbuf,
            u32* __restrict__ slots, int ring)
{
    __shared__ float gbuf[32 * 33];   // raw gates, +1 col pad

    const int tid  = threadIdx.x;
    const int wave = tid >> 6;
    const int lane = tid & 63;
    const int rt   = wave >> 1;       // row tile (batch 16*rt..)
    const int ct   = wave & 1;        // col tile (gate cols 16*ct..)
    const int quad = lane >> 4;
    const int l16  = lane & 15;
    const int hu0  = blockIdx.x * HU;

    // ---- B-operand fragments into registers (once), fp32 -> bf16 ----
    // block-local gate col: 0..31 = gate g (i,f,c,o) * 8 + unit u
    const int col = ct * 16 + l16;
    const int g   = col >> 3;
    const int u   = col & 7;
    const float* Ucol = ((g == 0) ? u_i : (g == 1) ? u_f : (g == 2) ? u_c : u_o) + hu0 + u;
    const float* Wcol = ((g == 0) ? w_i : (g == 1) ? w_f : (g == 2) ? w_c : w_o) + hu0 + u;

    bf16x8 bfr[48];                   // B[k = kb*32 + quad*8 + j][col]
    #pragma unroll
    for (int kb = 0; kb < 32; ++kb) { // K 0..1023: U rows
        #pragma unroll
        for (int j = 0; j < 8; ++j) {
            int k = kb * 32 + quad * 8 + j;
            bfr[kb][j] = (__bf16)Ucol[k * H_];
        }
    }
    #pragma unroll
    for (int kb = 32; kb < 48; ++kb) { // K 1024..1535: W rows
        #pragma unroll
        for (int j = 0; j < 8; ++j) {
            int k = kb * 32 + quad * 8 + j - 1024;
            bfr[kb][j] = (__bf16)Wcol[k * H_];
        }
    }

    // ---- update-phase ownership: thread -> (batch ub, unit uu) ----
    const int ub   = tid >> 3;        // batch 0..31
    const int uu   = tid & 7;         // unit  0..7
    const int unit = hu0 + uu;

    // h0 = 0 into ring slot 0 (coherent stores; drained by first barrier)
    if ((uu & 1) == 0) {
        u32* p0 = (u32*)hbuf + (ub * H_ + unit) / 2;
        __hip_atomic_store(p0, 0u, __ATOMIC_RELAXED, __HIP_MEMORY_SCOPE_AGENT);
    }

    const float bia = b_i[unit];
    const float bif = b_f[unit];
    const float bic = b_c[unit];
    const float bio = b_o[unit];
    float cstate = 0.0f;

    const int    arow = rt * 16 + l16;                    // batch row this lane feeds to A
    const float* xrow = X + arow * (S_ * I_) + quad * 8;  // A[m][k]: m=lane&15(+16rt), k=quad*8+j

    for (int t = 0; t < S_; ++t) {
        // arrival: __syncthreads drains ALL waves' h stores (compiler emits
        // vmcnt(0) before s_barrier), then thread 0 publishes the round.
        __syncthreads();
        if (tid == 0)
            __hip_atomic_store(&slots[blockIdx.x], (u32)(t + 1),
                               __ATOMIC_RELAXED, __HIP_MEMORY_SCOPE_AGENT);

        // ---- x_t @ W: h-independent, overlaps other blocks' arrival ----
        f32x4 acc = {0.f, 0.f, 0.f, 0.f};
        const float* xk = xrow + t * I_;
        #pragma unroll
        for (int kb = 0; kb < 16; ++kb) {
            f32x4 lo = *(const f32x4*)(xk + kb * 32);
            f32x4 hi = *(const f32x4*)(xk + kb * 32 + 4);
            bf16x8 a;
            a[0] = (__bf16)lo[0]; a[1] = (__bf16)lo[1];
            a[2] = (__bf16)lo[2]; a[3] = (__bf16)lo[3];
            a[4] = (__bf16)hi[0]; a[5] = (__bf16)hi[1];
            a[6] = (__bf16)hi[2]; a[7] = (__bf16)hi[3];
            acc = __builtin_amdgcn_mfma_f32_16x16x32_bf16(a, bfr[32 + kb], acc, 0, 0, 0);
        }

        // wait: lane j polls slot[j]. Signed compare: 0xAAAAAAAA poison < 1.
        if (tid < NBLK) {
            while ((int)__hip_atomic_load(&slots[tid], __ATOMIC_RELAXED,
                                          __HIP_MEMORY_SCOPE_AGENT) < (t + 1)) { }
        }
        __syncthreads();

        // ---- h(t-1) @ U ----
        const int rdslot = ring ? t : (t & 1);
        const u16* hb = hbuf + (size_t)rdslot * SLOT_ELEMS + arow * H_ + quad * 8;
        if (ring) {
            #pragma unroll
            for (int kb = 0; kb < 32; ++kb) {
                bf16x8 a = *(const bf16x8*)(hb + kb * 32);   // plain, cacheable
                acc = __builtin_amdgcn_mfma_f32_16x16x32_bf16(a, bfr[kb], acc, 0, 0, 0);
            }
        } else {
            const u32* hb32 = (const u32*)hb;
            #pragma unroll
            for (int kb = 0; kb < 32; ++kb) {
                union { u32 d[4]; bf16x8 v; } cv;
                #pragma unroll
                for (int w = 0; w < 4; ++w)
                    cv.d[w] = __hip_atomic_load(hb32 + kb * 16 + w,
                                                __ATOMIC_RELAXED, __HIP_MEMORY_SCOPE_AGENT);
                acc = __builtin_amdgcn_mfma_f32_16x16x32_bf16(cv.v, bfr[kb], acc, 0, 0, 0);
            }
        }

        // C/D layout: D[row = quad*4 + r][col = lane&15] (+16 per tile)
        {
            const int r0 = rt * 16 + quad * 4;
            #pragma unroll
            for (int r = 0; r < 4; ++r)
                gbuf[(r0 + r) * 33 + col] = acc[r];
        }
        __syncthreads();

        // gates -> c,h update (c stays in an fp32 register all 512 steps)
        {
            float gi = gbuf[ub * 33 + uu]      + bia;
            float gf = gbuf[ub * 33 + 8 + uu]  + bif;
            float gc = gbuf[ub * 33 + 16 + uu] + bic;
            float go = gbuf[ub * 33 + 24 + uu] + bio;
            float it  = sigmoid_(gi);
            float ft  = sigmoid_(gf);
            float ctl = tanh_(gc);
            float ot  = sigmoid_(go);
            cstate = ft * cstate + it * ctl;
            float h = ot * tanh_(cstate);

            // pack (even,odd) unit pair -> one coherent u32 store
            float hnb = __shfl_xor(h, 1);
            if ((uu & 1) == 0) {
                u32 pk = (u32)bf16bits(h) | ((u32)bf16bits(hnb) << 16);
                const int wrslot = ring ? (t + 1) : ((t + 1) & 1);
                u32* wp = (u32*)hbuf + ((size_t)wrslot * SLOT_ELEMS + ub * H_ + unit) / 2;
                __hip_atomic_store(wp, pk, __ATOMIC_RELAXED, __HIP_MEMORY_SCOPE_AGENT);
            }
            out[ub * (S_ * H_) + t * H_ + unit] = h;                     // fp32 hidden_seq
            if (t == S_ - 1) {
                out[B_ * S_ * H_ + ub * H_ + unit] = h;                  // h_t
                out[B_ * S_ * H_ + B_ * H_ + ub * H_ + unit] = cstate;   // c_t
            }
        }
        // next iteration's barrier separates this h(t) write from readers
    }
}

extern "C" void kernel_launch(void* const* d_in, const int* in_sizes, int n_in,
                              void* d_out, int out_size, void* d_ws, size_t ws_size,
                              hipStream_t stream) {
    const float* X   = (const float*)d_in[0];
    const float* w_i = (const float*)d_in[1];
    const float* u_i = (const float*)d_in[2];
    const float* b_i = (const float*)d_in[3];
    const float* w_f = (const float*)d_in[4];
    const float* u_f = (const float*)d_in[5];
    const float* b_f = (const float*)d_in[6];
    const float* w_c = (const float*)d_in[7];
    const float* u_c = (const float*)d_in[8];
    const float* b_c = (const float*)d_in[9];
    const float* w_o = (const float*)d_in[10];
    const float* u_o = (const float*)d_in[11];
    const float* b_o = (const float*)d_in[12];
    float* out = (float*)d_out;

    // ws layout: ring of (S_+1) h slots (64 KB each) if it fits, else 2 slots
    // (alternating, sc1-load fallback); then 128 barrier slot dwords.
    const size_t ring_bytes = (size_t)(S_ + 1) * SLOT_ELEMS * sizeof(u16); // 33.6 MB
    const size_t fb_bytes   = (size_t)2 * SLOT_ELEMS * sizeof(u16);        // 128 KB
    int ring = (ws_size >= ring_bytes + 1024) ? 1 : 0;
    size_t slots_off = ring ? ring_bytes : fb_bytes;

    u16* hbuf  = (u16*)d_ws;
    u32* slots = (u32*)((char*)d_ws + slots_off);

    hipLaunchKernelGGL(lstm_kernel, dim3(NBLK), dim3(256), 0, stream,
                       X, w_i, u_i, b_i, w_f, u_f, b_f, w_c, u_c, b_c,
                       w_o, u_o, b_o, out, hbuf, slots, ring);
}